// Round 15
// baseline (71.955 us; speedup 1.0000x reference)
//
#include <hip/hip_runtime.h>
#include <hip/hip_bf16.h>
#include <stdint.h>

#define E_ 11
#define B_ 16
#define S_ 256
#define H_ 1024
#define L_ 32
#define GEPS 1e-4f

typedef __attribute__((ext_vector_type(8))) short short8;
typedef __attribute__((ext_vector_type(4))) float f32x4;

__device__ __forceinline__ unsigned short f2bf(float f) {
  unsigned u = __float_as_uint(f);
  unsigned r = (u + 0x7FFFu + ((u >> 16) & 1u)) >> 16;  // RNE
  return (unsigned short)r;
}
__device__ __forceinline__ float bf2f(unsigned short v) {
  return __uint_as_float(((unsigned)v) << 16);
}
__device__ __forceinline__ void gload_lds16(const void* g, void* l) {
  __builtin_amdgcn_global_load_lds(
      (const __attribute__((address_space(1))) unsigned int*)g,
      (__attribute__((address_space(3))) unsigned int*)l, 16, 0, 0);
}
__device__ __forceinline__ float sigf(float x) { return 1.0f / (1.0f + expf(-x)); }

// lang_id soft-argmax for batch b
__device__ __forceinline__ float lang_of(const float* __restrict__ logits, int b) {
  float lv[E_];
  float m = -1e30f;
  #pragma unroll
  for (int i = 0; i < E_; ++i) { lv[i] = logits[b * E_ + i]; m = fmaxf(m, lv[i]); }
  float den = 0.f, num = 0.f;
  #pragma unroll
  for (int i = 0; i < E_; ++i) {
    float z = expf((lv[i] - m) * 1000.0f);
    den += z; num += z * (float)i;
  }
  return num / den;
}
__device__ __forceinline__ float gate_of(float lang, int e) {
  float fe = (float)e;
  return sigf((lang - (fe - 0.5f)) * 8.0f) * sigf(((fe + 0.5f) - lang) * 8.0f);
}

// conservative per-expert active flag (256-thread blocks)
__device__ __forceinline__ bool expert_active(const float* __restrict__ logits, int e) {
  int b = threadIdx.x & 15;
  float lang = lang_of(logits, b);
  unsigned long long m = __ballot(fabsf(lang - (float)e) < 1.7f);
  return m != 0ull;
}

// ---------------- prep: cvt_w1 + cvt_w2 + plan (x-cvt fused into ffn) ----------------
// W1T [E][d][k] bf16; W2T [E][l][k] bf16; plan: [cnt, pair0, ...]
// grid = 2816 (W1) + 176 (W2) + 1 (plan), 256 threads
__global__ __launch_bounds__(256) void prep_kernel(
    const float* __restrict__ logits,
    const float* __restrict__ W1, const float* __restrict__ W2,
    unsigned short* __restrict__ W1T, unsigned short* __restrict__ W2T,
    int* __restrict__ plan) {
  int bid = blockIdx.x;
  int tid = threadIdx.x;
  __shared__ float t[64][65];

  if (bid < 2816) {  // W1 [e][k][d] -> W1T bf16 [e][d][k]
    int tt = bid;
    int e = tt >> 8, rest = tt & 255;
    int k0 = (rest >> 4) * 64, d0 = (rest & 15) * 64;
    if (!expert_active(logits, e)) return;
    int kr = tid >> 2, dc = (tid & 3) * 16;
    const float* src = W1 + ((size_t)e << 20) + (size_t)(k0 + kr) * H_ + d0 + dc;
    #pragma unroll
    for (int q = 0; q < 4; ++q) {
      float4 v = *(const float4*)(src + q * 4);
      t[kr][dc + q * 4 + 0] = v.x; t[kr][dc + q * 4 + 1] = v.y;
      t[kr][dc + q * 4 + 2] = v.z; t[kr][dc + q * 4 + 3] = v.w;
    }
    __syncthreads();
    int dr = tid >> 2, kc = (tid & 3) * 16;
    short8 v0, v1;
    #pragma unroll
    for (int j = 0; j < 8; ++j) v0[j] = (short)f2bf(t[kc + j][dr]);
    #pragma unroll
    for (int j = 0; j < 8; ++j) v1[j] = (short)f2bf(t[kc + 8 + j][dr]);
    unsigned short* dst = W1T + ((size_t)e << 20) + (size_t)(d0 + dr) * H_ + k0 + kc;
    *(short8*)(dst) = v0;
    *(short8*)(dst + 8) = v1;
    return;
  }
  if (bid < 2816 + 176) {  // W2 [e][k][l] -> W2T bf16 [e][l][k]
    int tt = bid - 2816;
    int e = tt >> 4, k0 = (tt & 15) * 64;
    if (!expert_active(logits, e)) return;
    int kr = tid >> 2, lc = (tid & 3) * 8;
    const float* src = W2 + (size_t)e * H_ * L_ + (size_t)(k0 + kr) * L_ + lc;
    float4 a = *(const float4*)(src);
    float4 b = *(const float4*)(src + 4);
    t[kr][lc + 0] = a.x; t[kr][lc + 1] = a.y; t[kr][lc + 2] = a.z; t[kr][lc + 3] = a.w;
    t[kr][lc + 4] = b.x; t[kr][lc + 5] = b.y; t[kr][lc + 6] = b.z; t[kr][lc + 7] = b.w;
    __syncthreads();
    int lr = tid >> 3, kc = (tid & 7) * 8;
    short8 v;
    #pragma unroll
    for (int j = 0; j < 8; ++j) v[j] = (short)f2bf(t[kc + j][lr]);
    *(short8*)(W2T + (size_t)(e * L_ + lr) * H_ + k0 + kc) = v;
    return;
  }
  {  // plan block: ballot-compacted list of active (e,b) pairs, deterministic order
    __shared__ float langs[16];
    __shared__ int wcnt[4];
    if (tid < 16) langs[tid] = lang_of(logits, tid);
    __syncthreads();
    bool act = false;
    if (tid < E_ * B_) {
      int e = tid >> 4, b = tid & 15;
      act = gate_of(langs[b], e) >= GEPS;
    }
    unsigned long long m = __ballot(act);
    int w = tid >> 6;
    if ((tid & 63) == 0) wcnt[w] = __popcll(m);
    __syncthreads();
    int off = 0;
    for (int i = 0; i < w; ++i) off += wcnt[i];
    int rank = __popcll(m & ((1ull << (tid & 63)) - 1ull));
    if (act) plan[1 + off + rank] = tid;
    if (tid == 0) plan[0] = wcnt[0] + wcnt[1] + wcnt[2] + wcnt[3];
  }
}

// Fused sync: counted vmcnt + lgkmcnt(0) + s_barrier in ONE asm block with "memory"
// clobber (compile-time fence). lgkmcnt(0) retires ds_reads AND the A ds_writes
// before any wave passes the barrier -> ring overwrite is race-free.
#define SYNC_TILE(VM) \
  asm volatile("s_waitcnt vmcnt(" #VM ") lgkmcnt(0)\n\ts_barrier" ::: "memory")

// ===== fused gated FFN: 256x256 tile, ring-3, A reg-staged from RAW fp32 x (cvt fused) =====
// block = (active pair, dt): M=256 x N=256 x K=1024, BK=32. 512 thr = 8 waves (4wr x 2wc),
// wave-tile 64x128. LDS = 3 x 32KB = 96KB -> 1 block/CU.
// iter kt: cvt+ds_write A(kt+2) (regs loaded at kt-1; zero stall) -> issue A(kt+3) fp32
// loads -> B-DMA(kt+2) -> ds_read(kt) + 32 MFMA -> SYNC(6).
// vmcnt FIFO/iter = [A(kt+3)x4, B(kt+2)x2]; SYNC(6) retires B(kt+1) (the 2 oldest).
__global__ __launch_bounds__(512, 2) void ffn_kernel(
    const float* __restrict__ x, const unsigned short* __restrict__ W1T,
    const unsigned short* __restrict__ W2T, const float* __restrict__ b1,
    const float* __restrict__ b2, const float* __restrict__ logits,
    const int* __restrict__ plan, float* __restrict__ out) {
  int bid = blockIdx.x;
  int cnt = plan[0];
  if (bid >= (cnt << 2)) return;
  int pair = plan[1 + (bid >> 2)];
  int dt = bid & 3;
  int e = pair >> 4, b = pair & 15;
  float g = gate_of(lang_of(logits, b), e);

  __shared__ __align__(16) char smem[98304];  // 3 x 32KB

  int tid = threadIdx.x;
  int w = tid >> 6, wr = w >> 1, wc = w & 1;
  int l = tid & 63, l15 = l & 15, l4 = l >> 4;

  // ---- A: reg-staged from fp32 x. 2 chunks/thread (8 bf16 each after cvt) ----
  const float* gAf[2]; int ldsA[2];
  // ---- B: DMA-staged, 2 chunks/thread ----
  const unsigned short* gB[2]; int ldsB[2];
  #pragma unroll
  for (int jj = 0; jj < 2; ++jj) {
    int c = jj * 512 + tid;              // [0,1024)
    int p = c >> 3, uu = (c & 7) ^ (p & 7);
    int row = p * 2 + (uu >> 2), kc = (uu & 3) * 8;
    gAf[jj] = x + (size_t)(b * S_ + row) * H_ + kc;
    ldsA[jj] = c * 16;
    gB[jj] = W1T + ((size_t)e * H_ + dt * 256 + row) * H_ + kc;
    ldsB[jj] = 16384 + c * 16;
  }
  // ---- hoisted ds_read offsets (within one 32KB buffer) ----
  int offA[4], offB[8];
  #pragma unroll
  for (int mf = 0; mf < 4; ++mf) {
    int row = wr * 64 + mf * 16 + l15;   // [0,256)
    int p = row >> 1;
    int slot = (((row & 1) * 4) + l4) ^ (p & 7);
    offA[mf] = p * 128 + slot * 16;
  }
  #pragma unroll
  for (int nf = 0; nf < 8; ++nf) {
    int d = wc * 128 + nf * 16 + l15;    // [0,256)
    int p = d >> 1;
    int slot = (((d & 1) * 4) + l4) ^ (p & 7);
    offB[nf] = 16384 + p * 128 + slot * 16;
  }

  f32x4 acc[4][8];
  #pragma unroll
  for (int mf = 0; mf < 4; ++mf)
    #pragma unroll
    for (int nf = 0; nf < 8; ++nf) acc[mf][nf] = f32x4{0.f, 0.f, 0.f, 0.f};

  float4 ar[4];                          // A fp32 regs: chunk0 = ar[0..1], chunk1 = ar[2..3]
  auto ldA = [&](int kt) {
    int ko = kt * 32;
    ar[0] = *(const float4*)(gAf[0] + ko);
    ar[1] = *(const float4*)(gAf[0] + ko + 4);
    ar[2] = *(const float4*)(gAf[1] + ko);
    ar[3] = *(const float4*)(gAf[1] + ko + 4);
  };
  auto cvtWriteA = [&](int buf) {        // ar -> bf16, ds_write both chunks
    int bb = buf * 32768;
    uint4 w0, w1;
    asm("v_cvt_pk_bf16_f32 %0, %1, %2" : "=v"(w0.x) : "v"(ar[0].x), "v"(ar[0].y));
    asm("v_cvt_pk_bf16_f32 %0, %1, %2" : "=v"(w0.y) : "v"(ar[0].z), "v"(ar[0].w));
    asm("v_cvt_pk_bf16_f32 %0, %1, %2" : "=v"(w0.z) : "v"(ar[1].x), "v"(ar[1].y));
    asm("v_cvt_pk_bf16_f32 %0, %1, %2" : "=v"(w0.w) : "v"(ar[1].z), "v"(ar[1].w));
    asm("v_cvt_pk_bf16_f32 %0, %1, %2" : "=v"(w1.x) : "v"(ar[2].x), "v"(ar[2].y));
    asm("v_cvt_pk_bf16_f32 %0, %1, %2" : "=v"(w1.y) : "v"(ar[2].z), "v"(ar[2].w));
    asm("v_cvt_pk_bf16_f32 %0, %1, %2" : "=v"(w1.z) : "v"(ar[3].x), "v"(ar[3].y));
    asm("v_cvt_pk_bf16_f32 %0, %1, %2" : "=v"(w1.w) : "v"(ar[3].z), "v"(ar[3].w));
    *(uint4*)(smem + bb + ldsA[0]) = w0;
    *(uint4*)(smem + bb + ldsA[1]) = w1;
  };
  auto stageB = [&](int buf, int kt) {
    int bb = buf * 32768, ko = kt * 32;
    gload_lds16(gB[0] + ko, smem + bb + ldsB[0]);
    gload_lds16(gB[1] + ko, smem + bb + ldsB[1]);
  };

  // prologue: tiles 0,1 fully staged; A(2) loads in flight.
  ldA(0); cvtWriteA(0);
  ldA(1); cvtWriteA(1);
  stageB(0, 0);                          // FIFO: [B0 x2, ...]
  ldA(2);                                // [B0, A2 x4]
  __builtin_amdgcn_sched_barrier(0);
  stageB(1, 1);                          // [B0, A2, B1]
  SYNC_TILE(6);                          // retire B0; A2,B1 in flight; ds_writes drained

  #pragma unroll
  for (int kt = 0; kt < 32; ++kt) {
    if (kt < 30) cvtWriteA((kt + 2) % 3);  // waits A(kt+2) regs (vmcnt(2), issued last iter)
    if (kt < 29) ldA(kt + 3);
    __builtin_amdgcn_sched_barrier(0);     // pin FIFO: A-loads before B-DMA
    if (kt < 30) stageB((kt + 2) % 3, kt + 2);
    int bb = (kt % 3) * 32768;
    short8 af[4], bf[8];
    #pragma unroll
    for (int mf = 0; mf < 4; ++mf) af[mf] = *(const short8*)(smem + bb + offA[mf]);
    #pragma unroll
    for (int nf = 0; nf < 8; ++nf) bf[nf] = *(const short8*)(smem + bb + offB[nf]);
    // compiler interleaves lgkmcnt waits with the MFMAs (plain loads = known deps)
    #pragma unroll
    for (int mf = 0; mf < 4; ++mf)
      #pragma unroll
      for (int nf = 0; nf < 8; ++nf)
        acc[mf][nf] =
            __builtin_amdgcn_mfma_f32_16x16x32_bf16(af[mf], bf[nf], acc[mf][nf], 0, 0, 0);
    if (kt < 29) {
      SYNC_TILE(6);                      // retire B(kt+1); leave A(kt+3)x4 + B(kt+2)x2
    } else if (kt == 29) {
      SYNC_TILE(2);                      // retire B(30); leave B(31)x2
    } else if (kt == 30) {
      SYNC_TILE(0);                      // retire B(31)
    }
  }

  __syncthreads();  // ring about to be overlaid by P strips / Tred

  float b1v[8];
  #pragma unroll
  for (int nf = 0; nf < 8; ++nf)
    b1v[nf] = b1[e * H_ + dt * 256 + wc * 128 + nf * 16 + l15];

  // stage 2 in two 64-d halves: P strip (wave-private 8KB) -> tacc += P @ W2T
  char* P = smem + w * 8192;
  f32x4 tacc[4][2];
  #pragma unroll
  for (int mf = 0; mf < 4; ++mf)
    #pragma unroll
    for (int nl = 0; nl < 2; ++nl) tacc[mf][nl] = f32x4{0.f, 0.f, 0.f, 0.f};

  #pragma unroll
  for (int half = 0; half < 2; ++half) {
    #pragma unroll
    for (int mf = 0; mf < 4; ++mf)
      #pragma unroll
      for (int nfh = 0; nfh < 4; ++nfh) {
        int nf = half * 4 + nfh;
        #pragma unroll
        for (int rr = 0; rr < 4; ++rr) {
          int row = mf * 16 + l4 * 4 + rr;   // wave-local s row [0,64)
          int col = nfh * 16 + l15;          // half-local d [0,64)
          float v = fmaxf(acc[mf][nf][rr] + b1v[nf], 0.f);
          *(unsigned short*)(P + row * 128 + (((col >> 3) ^ (row & 7)) * 16) +
                             (col & 7) * 2) = f2bf(v);
        }
      }
    #pragma unroll
    for (int kk = 0; kk < 2; ++kk) {
      short8 ap[4], bw[2];
      #pragma unroll
      for (int mf = 0; mf < 4; ++mf) {
        int row = mf * 16 + l15;
        int ch = kk * 4 + l4;
        ap[mf] = *(const short8*)(P + row * 128 + ((ch ^ (row & 7)) * 16));
      }
      #pragma unroll
      for (int nl = 0; nl < 2; ++nl)
        bw[nl] = *(const short8*)(W2T + (size_t)(e * L_ + nl * 16 + l15) * H_ +
                                  dt * 256 + wc * 128 + half * 64 + kk * 32 + l4 * 8);
      #pragma unroll
      for (int mf = 0; mf < 4; ++mf)
        #pragma unroll
        for (int nl = 0; nl < 2; ++nl)
          tacc[mf][nl] =
              __builtin_amdgcn_mfma_f32_16x16x32_bf16(ap[mf], bw[nl], tacc[mf][nl], 0, 0, 0);
    }
  }

  // per-wave t (64x32 f32 = 8KB, overlays own P), cross-wc reduce, atomicAdd
  float* Tr = (float*)smem + w * 2048;
  #pragma unroll
  for (int mf = 0; mf < 4; ++mf)
    #pragma unroll
    for (int nl = 0; nl < 2; ++nl)
      #pragma unroll
      for (int rr = 0; rr < 4; ++rr) {
        int row = mf * 16 + l4 * 4 + rr;
        int col = nl * 16 + l15;
        Tr[row * 32 + col] = tacc[mf][nl][rr];
      }
  __syncthreads();
  float* Tb = (float*)smem;
  #pragma unroll
  for (int jj = 0; jj < 16; ++jj) {
    int ei = tid + jj * 512;                 // [0,8192) = 256 rows x 32 cols
    int srow = ei >> 5, lcol = ei & 31;
    int wr2 = srow >> 6, r6 = srow & 63;
    float sum = Tb[(wr2 * 2 + 0) * 2048 + r6 * 32 + lcol] +
                Tb[(wr2 * 2 + 1) * 2048 + r6 * 32 + lcol];
    if (dt == 0) sum += b2[e * L_ + lcol];
    atomicAdd(out + (size_t)(b * S_ + srow) * L_ + lcol, g * sum);
  }
}

// ---------------- fp32 fallback (no workspace needed) ----------------
__global__ void fb_kernel(const float* __restrict__ x, const float* __restrict__ logits,
                          const float* __restrict__ W1, const float* __restrict__ b1,
                          const float* __restrict__ W2, const float* __restrict__ b2,
                          float* __restrict__ out) {
  int bid = blockIdx.x;
  int e = bid >> 9;
  int r = bid & 511;
  int b = r >> 5, st = r & 31, s0 = st * 8;
  float g = gate_of(lang_of(logits, b), e);
  if (g < GEPS) return;

  __shared__ float xs[8][H_];
  __shared__ unsigned short hs[8][H_];
  int tid = threadIdx.x;
  for (int jj = 0; jj < 32; ++jj) {
    int idx = tid + jj * 256;
    int s = idx >> 10, k = idx & 1023;
    xs[s][k] = x[(size_t)(b * S_ + s0 + s) * H_ + k];
  }
  __syncthreads();
  for (int qq = 0; qq < 4; ++qq) {
    int d = tid + qq * 256;
    float a[8];
    #pragma unroll
    for (int s = 0; s < 8; ++s) a[s] = 0.f;
    for (int k = 0; k < H_; ++k) {
      float wv = W1[((size_t)e << 20) + (size_t)k * H_ + d];
      #pragma unroll
      for (int s = 0; s < 8; ++s) a[s] += xs[s][k] * wv;
    }
    float bv = b1[e * H_ + d];
    #pragma unroll
    for (int s = 0; s < 8; ++s) hs[s][d] = f2bf(fmaxf(a[s] + bv, 0.f));
  }
  __syncthreads();
  int s = tid >> 5, lcol = tid & 31;
  float acc = 0.f;
  for (int d = 0; d < H_; ++d)
    acc += bf2f(hs[s][d]) * W2[(size_t)(e * H_ + d) * L_ + lcol];
  acc += b2[e * L_ + lcol];
  atomicAdd(out + (size_t)(b * S_ + s0 + s) * L_ + lcol, g * acc);
}

extern "C" void kernel_launch(void* const* d_in, const int* in_sizes, int n_in,
                              void* d_out, int out_size, void* d_ws, size_t ws_size,
                              hipStream_t stream) {
  (void)in_sizes; (void)n_in;
  const float* x  = (const float*)d_in[0];
  const float* lg = (const float*)d_in[1];
  const float* W1 = (const float*)d_in[2];
  const float* b1 = (const float*)d_in[3];
  const float* W2 = (const float*)d_in[4];
  const float* b2 = (const float*)d_in[5];
  float* out = (float*)d_out;

  hipMemsetAsync(d_out, 0, (size_t)out_size * sizeof(float), stream);

  const size_t OFF_W1 = 0;                         // 22 MB bf16 W1T
  const size_t OFF_W2 = OFF_W1 + 23068672;         // 704 KB bf16 W2T
  const size_t OFF_PLAN = OFF_W2 + 720896;         // [cnt, pairs...]
  const size_t WS_NEED = OFF_PLAN + 1024;

  if (ws_size >= WS_NEED) {
    unsigned short* W1T = (unsigned short*)((char*)d_ws + OFF_W1);
    unsigned short* W2T = (unsigned short*)((char*)d_ws + OFF_W2);
    int* plan = (int*)((char*)d_ws + OFF_PLAN);
    prep_kernel<<<2816 + 176 + 1, 256, 0, stream>>>(lg, W1, W2, W1T, W2T, plan);
    // worst case 176 pairs x 4 dt; blocks beyond 4*cnt exit on plan[0]
    ffn_kernel<<<704, 512, 0, stream>>>(x, W1T, W2T, b1, b2, lg, plan, out);
  } else {
    fb_kernel<<<E_ * B_ * (S_ / 8), 256, 0, stream>>>(x, lg, W1, b1, W2, b2, out);
  }
}

// Round 16
// 56.924 us; speedup vs baseline: 1.2641x; 1.2641x over previous
//
#include <hip/hip_runtime.h>
#include <hip/hip_bf16.h>
#include <stdint.h>

#define E_ 11
#define B_ 16
#define S_ 256
#define H_ 1024
#define L_ 32
#define GEPS 1e-4f

typedef __attribute__((ext_vector_type(8))) short short8;
typedef __attribute__((ext_vector_type(4))) float f32x4;

__device__ __forceinline__ unsigned short f2bf(float f) {
  unsigned u = __float_as_uint(f);
  unsigned r = (u + 0x7FFFu + ((u >> 16) & 1u)) >> 16;  // RNE
  return (unsigned short)r;
}
__device__ __forceinline__ float bf2f(unsigned short v) {
  return __uint_as_float(((unsigned)v) << 16);
}
__device__ __forceinline__ void gload_lds16(const void* g, void* l) {
  __builtin_amdgcn_global_load_lds(
      (const __attribute__((address_space(1))) unsigned int*)g,
      (__attribute__((address_space(3))) unsigned int*)l, 16, 0, 0);
}
__device__ __forceinline__ float sigf(float x) { return 1.0f / (1.0f + expf(-x)); }

// lang_id soft-argmax for batch b
__device__ __forceinline__ float lang_of(const float* __restrict__ logits, int b) {
  float lv[E_];
  float m = -1e30f;
  #pragma unroll
  for (int i = 0; i < E_; ++i) { lv[i] = logits[b * E_ + i]; m = fmaxf(m, lv[i]); }
  float den = 0.f, num = 0.f;
  #pragma unroll
  for (int i = 0; i < E_; ++i) {
    float z = expf((lv[i] - m) * 1000.0f);
    den += z; num += z * (float)i;
  }
  return num / den;
}
__device__ __forceinline__ float gate_of(float lang, int e) {
  float fe = (float)e;
  return sigf((lang - (fe - 0.5f)) * 8.0f) * sigf(((fe + 0.5f) - lang) * 8.0f);
}

// conservative per-expert active flag (256-thread blocks)
__device__ __forceinline__ bool expert_active(const float* __restrict__ logits, int e) {
  int b = threadIdx.x & 15;
  float lang = lang_of(logits, b);
  unsigned long long m = __ballot(fabsf(lang - (float)e) < 1.7f);
  return m != 0ull;
}

// ------- prep: cvt_x + cvt_w1 + cvt_w2 + plan + out-zeroing (memset folded in) -------
// xbf [B][S][H] bf16; W1T [E][d][k] bf16; W2T [E][l][k] bf16; plan: [cnt, pair0, ...]
// grid = 2048 (x) + 2816 (W1) + 176 (W2) + 1 (plan) + 128 (zero out), 256 threads
__global__ __launch_bounds__(256) void prep_kernel(
    const float* __restrict__ x, const float* __restrict__ logits,
    const float* __restrict__ W1, const float* __restrict__ W2,
    unsigned short* __restrict__ xbf, unsigned short* __restrict__ W1T,
    unsigned short* __restrict__ W2T, int* __restrict__ plan,
    float* __restrict__ out) {
  int bid = blockIdx.x;
  int tid = threadIdx.x;
  __shared__ float t[64][65];

  if (bid < 2048) {  // x -> bf16
    int i = (bid * 256 + tid) * 8;
    float4 f0 = *(const float4*)(x + i);
    float4 f1 = *(const float4*)(x + i + 4);
    short8 o;
    o[0] = (short)f2bf(f0.x); o[1] = (short)f2bf(f0.y);
    o[2] = (short)f2bf(f0.z); o[3] = (short)f2bf(f0.w);
    o[4] = (short)f2bf(f1.x); o[5] = (short)f2bf(f1.y);
    o[6] = (short)f2bf(f1.z); o[7] = (short)f2bf(f1.w);
    *(short8*)(xbf + i) = o;
    return;
  }
  if (bid < 2048 + 2816) {  // W1 [e][k][d] -> W1T bf16 [e][d][k]
    int tt = bid - 2048;
    int e = tt >> 8, rest = tt & 255;
    int k0 = (rest >> 4) * 64, d0 = (rest & 15) * 64;
    if (!expert_active(logits, e)) return;
    int kr = tid >> 2, dc = (tid & 3) * 16;
    const float* src = W1 + ((size_t)e << 20) + (size_t)(k0 + kr) * H_ + d0 + dc;
    #pragma unroll
    for (int q = 0; q < 4; ++q) {
      float4 v = *(const float4*)(src + q * 4);
      t[kr][dc + q * 4 + 0] = v.x; t[kr][dc + q * 4 + 1] = v.y;
      t[kr][dc + q * 4 + 2] = v.z; t[kr][dc + q * 4 + 3] = v.w;
    }
    __syncthreads();
    int dr = tid >> 2, kc = (tid & 3) * 16;
    short8 v0, v1;
    #pragma unroll
    for (int j = 0; j < 8; ++j) v0[j] = (short)f2bf(t[kc + j][dr]);
    #pragma unroll
    for (int j = 0; j < 8; ++j) v1[j] = (short)f2bf(t[kc + 8 + j][dr]);
    unsigned short* dst = W1T + ((size_t)e << 20) + (size_t)(d0 + dr) * H_ + k0 + kc;
    *(short8*)(dst) = v0;
    *(short8*)(dst + 8) = v1;
    return;
  }
  if (bid < 2048 + 2816 + 176) {  // W2 [e][k][l] -> W2T bf16 [e][l][k]
    int tt = bid - 4864;
    int e = tt >> 4, k0 = (tt & 15) * 64;
    if (!expert_active(logits, e)) return;
    int kr = tid >> 2, lc = (tid & 3) * 8;
    const float* src = W2 + (size_t)e * H_ * L_ + (size_t)(k0 + kr) * L_ + lc;
    float4 a = *(const float4*)(src);
    float4 b = *(const float4*)(src + 4);
    t[kr][lc + 0] = a.x; t[kr][lc + 1] = a.y; t[kr][lc + 2] = a.z; t[kr][lc + 3] = a.w;
    t[kr][lc + 4] = b.x; t[kr][lc + 5] = b.y; t[kr][lc + 6] = b.z; t[kr][lc + 7] = b.w;
    __syncthreads();
    int lr = tid >> 3, kc = (tid & 7) * 8;
    short8 v;
    #pragma unroll
    for (int j = 0; j < 8; ++j) v[j] = (short)f2bf(t[kc + j][lr]);
    *(short8*)(W2T + (size_t)(e * L_ + lr) * H_ + k0 + kc) = v;
    return;
  }
  if (bid == 2048 + 2816 + 176) {  // plan: ballot-compacted active (e,b) list
    __shared__ float langs[16];
    __shared__ int wcnt[4];
    if (tid < 16) langs[tid] = lang_of(logits, tid);
    __syncthreads();
    bool act = false;
    if (tid < E_ * B_) {
      int e = tid >> 4, b = tid & 15;
      act = gate_of(langs[b], e) >= GEPS;
    }
    unsigned long long m = __ballot(act);
    int w = tid >> 6;
    if ((tid & 63) == 0) wcnt[w] = __popcll(m);
    __syncthreads();
    int off = 0;
    for (int i = 0; i < w; ++i) off += wcnt[i];
    int rank = __popcll(m & ((1ull << (tid & 63)) - 1ull));
    if (act) plan[1 + off + rank] = tid;
    if (tid == 0) plan[0] = wcnt[0] + wcnt[1] + wcnt[2] + wcnt[3];
    return;
  }
  {  // zero out (replaces hipMemsetAsync): 128 blocks x 256 thr x 4 floats = 131072
    int zb = bid - (2048 + 2816 + 176 + 1);
    int i = (zb * 256 + tid) * 4;
    *(float4*)(out + i) = float4{0.f, 0.f, 0.f, 0.f};
  }
}

// Fused sync: counted vmcnt + lgkmcnt(0) + s_barrier in ONE asm block with "memory"
// clobber (compile-time fence; no LDS/DMA op crosses). lgkmcnt(0) guarantees ds_reads
// retired before any wave passes the barrier -> ring overwrite is race-free. vmcnt
// stays counted (never a full mid-loop drain).
#define SYNC_TILE(VM) \
  asm volatile("s_waitcnt vmcnt(" #VM ") lgkmcnt(0)\n\ts_barrier" ::: "memory")

// ===== fused gated FFN (best measured config, R10 geometry + race-free sync) =====
// block = (active pair, dt): M=256 x N=256 x K=1024, BK=32. 512 thr = 8 waves (4wr x 2wc),
// wave-tile 64x128. LDS = 3 x 32KB ring = 96KB -> 1 block/CU (176 active blocks, balanced).
// iter kt: stage(kt+2) -> ds_read(kt) + 32 MFMA (compiler-interleaved lgkm waits) ->
// SYNC_TILE(4) (tile kt+1 landed; kt+2 in flight).
__global__ __launch_bounds__(512, 2) void ffn_kernel(
    const unsigned short* __restrict__ xbf, const unsigned short* __restrict__ W1T,
    const unsigned short* __restrict__ W2T, const float* __restrict__ b1,
    const float* __restrict__ b2, const float* __restrict__ logits,
    const int* __restrict__ plan, float* __restrict__ out) {
  int bid = blockIdx.x;
  int cnt = plan[0];
  if (bid >= (cnt << 2)) return;
  int pair = plan[1 + (bid >> 2)];
  int dt = bid & 3;
  int e = pair >> 4, b = pair & 15;
  float g = gate_of(lang_of(logits, b), e);

  __shared__ __align__(16) char smem[98304];  // 3 x 32KB

  int tid = threadIdx.x;
  int w = tid >> 6, wr = w >> 1, wc = w & 1;
  int l = tid & 63, l15 = l & 15, l4 = l >> 4;

  // ---- hoisted staging addresses: A 2 chunks/thread, B 2 chunks/thread ----
  const unsigned short* gA[2]; int ldsA[2];
  const unsigned short* gB[2]; int ldsB[2];
  #pragma unroll
  for (int jj = 0; jj < 2; ++jj) {
    int c = jj * 512 + tid;              // [0,1024)
    int p = c >> 3, uu = (c & 7) ^ (p & 7);
    int row = p * 2 + (uu >> 2), kc = (uu & 3) * 8;
    gA[jj] = xbf + (size_t)(b * S_ + row) * H_ + kc;
    ldsA[jj] = c * 16;
    gB[jj] = W1T + ((size_t)e * H_ + dt * 256 + row) * H_ + kc;
    ldsB[jj] = 16384 + c * 16;
  }
  // ---- hoisted ds_read offsets (within one 32KB buffer) ----
  int offA[4], offB[8];
  #pragma unroll
  for (int mf = 0; mf < 4; ++mf) {
    int row = wr * 64 + mf * 16 + l15;   // [0,256)
    int p = row >> 1;
    int slot = (((row & 1) * 4) + l4) ^ (p & 7);
    offA[mf] = p * 128 + slot * 16;
  }
  #pragma unroll
  for (int nf = 0; nf < 8; ++nf) {
    int d = wc * 128 + nf * 16 + l15;    // [0,256)
    int p = d >> 1;
    int slot = (((d & 1) * 4) + l4) ^ (p & 7);
    offB[nf] = 16384 + p * 128 + slot * 16;
  }

  f32x4 acc[4][8];
  #pragma unroll
  for (int mf = 0; mf < 4; ++mf)
    #pragma unroll
    for (int nf = 0; nf < 8; ++nf) acc[mf][nf] = f32x4{0.f, 0.f, 0.f, 0.f};

  auto stage = [&](int buf, int kt) {
    int bb = buf * 32768;
    int ko = kt * 32;
    gload_lds16(gA[0] + ko, smem + bb + ldsA[0]);
    gload_lds16(gA[1] + ko, smem + bb + ldsA[1]);
    gload_lds16(gB[0] + ko, smem + bb + ldsB[0]);
    gload_lds16(gB[1] + ko, smem + bb + ldsB[1]);
  };

  stage(0, 0);
  stage(1, 1);
  SYNC_TILE(4);                              // tile 0 landed; tile 1 in flight

  #pragma unroll
  for (int kt = 0; kt < 32; ++kt) {
    if (kt < 30) stage((kt + 2) % 3, kt + 2);
    int bb = (kt % 3) * 32768;
    short8 af[4], bf[8];
    #pragma unroll
    for (int mf = 0; mf < 4; ++mf) af[mf] = *(const short8*)(smem + bb + offA[mf]);
    #pragma unroll
    for (int nf = 0; nf < 8; ++nf) bf[nf] = *(const short8*)(smem + bb + offB[nf]);
    // compiler interleaves lgkmcnt waits with the MFMAs (plain loads = known deps)
    #pragma unroll
    for (int mf = 0; mf < 4; ++mf)
      #pragma unroll
      for (int nf = 0; nf < 8; ++nf)
        acc[mf][nf] =
            __builtin_amdgcn_mfma_f32_16x16x32_bf16(af[mf], bf[nf], acc[mf][nf], 0, 0, 0);
    if (kt < 30) {
      SYNC_TILE(4);                          // tile kt+1 landed; kt+2 in flight
    } else if (kt == 30) {
      SYNC_TILE(0);                          // tile 31 landed
    }
  }

  __syncthreads();  // ring about to be overlaid by P strips / Tred

  float b1v[8];
  #pragma unroll
  for (int nf = 0; nf < 8; ++nf)
    b1v[nf] = b1[e * H_ + dt * 256 + wc * 128 + nf * 16 + l15];

  // stage 2 in two 64-d halves: P strip (wave-private 8KB) -> tacc += P @ W2T
  char* P = smem + w * 8192;
  f32x4 tacc[4][2];
  #pragma unroll
  for (int mf = 0; mf < 4; ++mf)
    #pragma unroll
    for (int nl = 0; nl < 2; ++nl) tacc[mf][nl] = f32x4{0.f, 0.f, 0.f, 0.f};

  #pragma unroll
  for (int half = 0; half < 2; ++half) {
    #pragma unroll
    for (int mf = 0; mf < 4; ++mf)
      #pragma unroll
      for (int nfh = 0; nfh < 4; ++nfh) {
        int nf = half * 4 + nfh;
        #pragma unroll
        for (int rr = 0; rr < 4; ++rr) {
          int row = mf * 16 + l4 * 4 + rr;   // wave-local s row [0,64)
          int col = nfh * 16 + l15;          // half-local d [0,64)
          float v = fmaxf(acc[mf][nf][rr] + b1v[nf], 0.f);
          *(unsigned short*)(P + row * 128 + (((col >> 3) ^ (row & 7)) * 16) +
                             (col & 7) * 2) = f2bf(v);
        }
      }
    #pragma unroll
    for (int kk = 0; kk < 2; ++kk) {
      short8 ap[4], bw[2];
      #pragma unroll
      for (int mf = 0; mf < 4; ++mf) {
        int row = mf * 16 + l15;
        int ch = kk * 4 + l4;
        ap[mf] = *(const short8*)(P + row * 128 + ((ch ^ (row & 7)) * 16));
      }
      #pragma unroll
      for (int nl = 0; nl < 2; ++nl)
        bw[nl] = *(const short8*)(W2T + (size_t)(e * L_ + nl * 16 + l15) * H_ +
                                  dt * 256 + wc * 128 + half * 64 + kk * 32 + l4 * 8);
      #pragma unroll
      for (int mf = 0; mf < 4; ++mf)
        #pragma unroll
        for (int nl = 0; nl < 2; ++nl)
          tacc[mf][nl] =
              __builtin_amdgcn_mfma_f32_16x16x32_bf16(ap[mf], bw[nl], tacc[mf][nl], 0, 0, 0);
    }
  }

  // per-wave t (64x32 f32 = 8KB, overlays own P), cross-wc reduce, atomicAdd
  float* Tr = (float*)smem + w * 2048;
  #pragma unroll
  for (int mf = 0; mf < 4; ++mf)
    #pragma unroll
    for (int nl = 0; nl < 2; ++nl)
      #pragma unroll
      for (int rr = 0; rr < 4; ++rr) {
        int row = mf * 16 + l4 * 4 + rr;
        int col = nl * 16 + l15;
        Tr[row * 32 + col] = tacc[mf][nl][rr];
      }
  __syncthreads();
  float* Tb = (float*)smem;
  #pragma unroll
  for (int jj = 0; jj < 16; ++jj) {
    int ei = tid + jj * 512;                 // [0,8192) = 256 rows x 32 cols
    int srow = ei >> 5, lcol = ei & 31;
    int wr2 = srow >> 6, r6 = srow & 63;
    float sum = Tb[(wr2 * 2 + 0) * 2048 + r6 * 32 + lcol] +
                Tb[(wr2 * 2 + 1) * 2048 + r6 * 32 + lcol];
    if (dt == 0) sum += b2[e * L_ + lcol];
    atomicAdd(out + (size_t)(b * S_ + srow) * L_ + lcol, g * sum);
  }
}

// ---------------- fp32 fallback (no workspace needed) ----------------
__global__ void fb_kernel(const float* __restrict__ x, const float* __restrict__ logits,
                          const float* __restrict__ W1, const float* __restrict__ b1,
                          const float* __restrict__ W2, const float* __restrict__ b2,
                          float* __restrict__ out) {
  int bid = blockIdx.x;
  int e = bid >> 9;
  int r = bid & 511;
  int b = r >> 5, st = r & 31, s0 = st * 8;
  float g = gate_of(lang_of(logits, b), e);
  if (g < GEPS) return;

  __shared__ float xs[8][H_];
  __shared__ unsigned short hs[8][H_];
  int tid = threadIdx.x;
  for (int jj = 0; jj < 32; ++jj) {
    int idx = tid + jj * 256;
    int s = idx >> 10, k = idx & 1023;
    xs[s][k] = x[(size_t)(b * S_ + s0 + s) * H_ + k];
  }
  __syncthreads();
  for (int qq = 0; qq < 4; ++qq) {
    int d = tid + qq * 256;
    float a[8];
    #pragma unroll
    for (int s = 0; s < 8; ++s) a[s] = 0.f;
    for (int k = 0; k < H_; ++k) {
      float wv = W1[((size_t)e << 20) + (size_t)k * H_ + d];
      #pragma unroll
      for (int s = 0; s < 8; ++s) a[s] += xs[s][k] * wv;
    }
    float bv = b1[e * H_ + d];
    #pragma unroll
    for (int s = 0; s < 8; ++s) hs[s][d] = f2bf(fmaxf(a[s] + bv, 0.f));
  }
  __syncthreads();
  int s = tid >> 5, lcol = tid & 31;
  float acc = 0.f;
  for (int d = 0; d < H_; ++d)
    acc += bf2f(hs[s][d]) * W2[(size_t)(e * H_ + d) * L_ + lcol];
  acc += b2[e * L_ + lcol];
  atomicAdd(out + (size_t)(b * S_ + s0 + s) * L_ + lcol, g * acc);
}

extern "C" void kernel_launch(void* const* d_in, const int* in_sizes, int n_in,
                              void* d_out, int out_size, void* d_ws, size_t ws_size,
                              hipStream_t stream) {
  (void)in_sizes; (void)n_in;
  const float* x  = (const float*)d_in[0];
  const float* lg = (const float*)d_in[1];
  const float* W1 = (const float*)d_in[2];
  const float* b1 = (const float*)d_in[3];
  const float* W2 = (const float*)d_in[4];
  const float* b2 = (const float*)d_in[5];
  float* out = (float*)d_out;

  const size_t OFF_X = 0;                          // 8 MB bf16 x
  const size_t OFF_W1 = OFF_X + 8388608;           // 22 MB bf16 W1T
  const size_t OFF_W2 = OFF_W1 + 23068672;         // 704 KB bf16 W2T
  const size_t OFF_PLAN = OFF_W2 + 720896;         // [cnt, pairs...]
  const size_t WS_NEED = OFF_PLAN + 1024;

  if (ws_size >= WS_NEED) {
    unsigned short* xbf = (unsigned short*)((char*)d_ws + OFF_X);
    unsigned short* W1T = (unsigned short*)((char*)d_ws + OFF_W1);
    unsigned short* W2T = (unsigned short*)((char*)d_ws + OFF_W2);
    int* plan = (int*)((char*)d_ws + OFF_PLAN);
    // prep also zeroes `out` (128 tail blocks) — no separate memset dispatch
    prep_kernel<<<2048 + 2816 + 176 + 1 + 128, 256, 0, stream>>>(
        x, lg, W1, W2, xbf, W1T, W2T, plan, out);
    // worst case 176 pairs x 4 dt; blocks beyond 4*cnt exit on plan[0]
    ffn_kernel<<<704, 512, 0, stream>>>(xbf, W1T, W2T, b1, b2, lg, plan, out);
  } else {
    hipMemsetAsync(d_out, 0, (size_t)out_size * sizeof(float), stream);
    fb_kernel<<<E_ * B_ * (S_ / 8), 256, 0, stream>>>(x, lg, W1, b1, W2, b2, out);
  }
}